// Round 8
// baseline (372.130 us; speedup 1.0000x reference)
//
#include <hip/hip_runtime.h>

// ---------------------------------------------------------------------------
// EncoderLayer on MI355X (gfx950). fp32 in/out, bf16 MFMA compute inside.
// B=4 S=2048 D=768 H=12 Dk=64 Dff=2048, M = B*S = 8192 tokens.
//
// Round 8: GEMM K-loop rebuilt on the attn-validated staging pattern:
// register prefetch -> ds_write_b128 commit, double-buffered LDS, ONE
// barrier per BK=32 iter, padded LDS rows (stride 40 u16, ~conflict-free).
// Residual fusion (r7) kept. Launch bounds: 128-tile (256,3), 64-tile (256,4).
// ---------------------------------------------------------------------------

typedef unsigned short u16;
typedef __bf16 bf16x8 __attribute__((ext_vector_type(8)));
typedef __bf16 bf16x4 __attribute__((ext_vector_type(4)));
typedef unsigned short u16x8 __attribute__((ext_vector_type(8)));
typedef float f32x4 __attribute__((ext_vector_type(4)));

#define D_MODEL 768
#define D_FF    2048
#define NH      12
#define DK      64
#define S_LEN   2048
#define M_TOK   8192

#define QSCALE   0.18033688011112042f   /* 0.125 * log2(e) */
#define MSCALE  -1.4426950408889634e9f  /* -1e9 * log2(e)  */

#define RS 40   /* GEMM LDS row stride in u16: 80 B -> bank step 20 (mod 32), no hot banks */

__device__ __forceinline__ float bf2f(u16 v) {
    union { unsigned u; float f; } c; c.u = ((unsigned)v) << 16; return c.f;
}
__device__ __forceinline__ void st_bf(u16* p, float v) { *(__bf16*)p = (__bf16)v; }

// ---------------------------------------------------------------------------
// Fused prep: blocks [0,2304) = 4x 768x768 transposes; [2304,3840) = W1;
// [3840,5376) = W2; [5376,11520) = x fp32->bf16.
// ---------------------------------------------------------------------------
__global__ __launch_bounds__(256)
void prep_k(const float* __restrict__ x, const float* __restrict__ Wq,
            const float* __restrict__ Wk, const float* __restrict__ Wv,
            const float* __restrict__ Wo, const float* __restrict__ W1,
            const float* __restrict__ W2, u16* __restrict__ xb,
            u16* __restrict__ WqkvT, u16* __restrict__ WoT,
            u16* __restrict__ W1T, u16* __restrict__ W2T) {
    __shared__ float t[32][33];
    const int id = blockIdx.x, tid = threadIdx.x;
    if (id >= 5376) {               // ---- x convert ----
        const int i = ((id - 5376) * 256 + tid) * 4;
        const float4 v = *(const float4*)(x + i);
        __bf16 o[4] = {(__bf16)v.x, (__bf16)v.y, (__bf16)v.z, (__bf16)v.w};
        *(bf16x4*)(xb + i) = *(bf16x4*)o;
        return;
    }
    const float* in; u16* out; int R, C, bx, by;
    if (id < 2304) {                // ---- Wq/Wk/Wv/Wo 768x768 ----
        const int z = id / 576, r = id % 576;
        in = z == 0 ? Wq : (z == 1 ? Wk : (z == 2 ? Wv : Wo));
        out = z == 3 ? WoT : WqkvT + z * 768 * 768;
        R = 768; C = 768; bx = (r % 24) * 32; by = (r / 24) * 32;
    } else if (id < 3840) {         // ---- W1 [768,2048] -> [2048,768] ----
        const int r = id - 2304;
        in = W1; out = W1T; R = 768; C = 2048;
        bx = (r % 64) * 32; by = (r / 64) * 32;
    } else {                        // ---- W2 [2048,768] -> [768,2048] ----
        const int r = id - 3840;
        in = W2; out = W2T; R = 2048; C = 768;
        bx = (r % 24) * 32; by = (r / 24) * 32;
    }
    const int tx = tid & 31, ty = tid >> 5;
#pragma unroll
    for (int i = 0; i < 32; i += 8)
        t[ty + i][tx] = in[(size_t)(by + ty + i) * C + bx + tx];
    __syncthreads();
#pragma unroll
    for (int i = 0; i < 32; i += 8)
        st_bf(&out[(size_t)(bx + ty + i) * R + by + tx], t[tx][ty + i]);
}

// ---------------------------------------------------------------------------
// Fused QKV GEMM, 128x128 tile, BK=32 double-buffered reg-prefetch staging,
// one barrier per iter. n-sel: Q*QSCALE / K / V (pre-transposed [B,H,Dk,S]).
// ---------------------------------------------------------------------------
__global__ __launch_bounds__(256, 3)
void qkv_gemm_k(const u16* __restrict__ A, const u16* __restrict__ Bt,
                const float* __restrict__ bq, const float* __restrict__ bk,
                const float* __restrict__ bv, u16* __restrict__ Qb,
                u16* __restrict__ Kb, u16* __restrict__ Vt) {
    __shared__ __align__(16) u16 As[2][128 * RS];   // 20 KB
    __shared__ __align__(16) u16 Bs[2][128 * RS];   // 20 KB
    const int tid = threadIdx.x;
    const int lane = tid & 63, w = tid >> 6;
    const int r16 = lane & 15, qd = lane >> 4;
    const int m0 = blockIdx.x * 128, n0 = blockIdx.y * 128;
    const int wm = (w & 1) << 6, wn = (w >> 1) << 6;
    const int K = D_MODEL;

    f32x4 acc[4][4] = {};

    const int srow = tid >> 1, scol = (tid & 1) << 4;    // 128 rows x {0,16}
    const u16* aP = A  + (size_t)(m0 + srow) * K + scol;
    const u16* bP = Bt + (size_t)(n0 + srow) * K + scol;
    const int lds_off = srow * RS + scol;

    u16x8 ar0 = *(const u16x8*)(aP);     u16x8 ar1 = *(const u16x8*)(aP + 8);
    u16x8 br0 = *(const u16x8*)(bP);     u16x8 br1 = *(const u16x8*)(bP + 8);

    for (int k0 = 0, it = 0; k0 < K; k0 += 32, ++it) {
        const int buf = it & 1;
        // commit prefetched tile
        *(u16x8*)&As[buf][lds_off]     = ar0;
        *(u16x8*)&As[buf][lds_off + 8] = ar1;
        *(u16x8*)&Bs[buf][lds_off]     = br0;
        *(u16x8*)&Bs[buf][lds_off + 8] = br1;
        __syncthreads();
        // prefetch next tile (issued after barrier, drained at next barrier)
        if (k0 + 32 < K) {
            ar0 = *(const u16x8*)(aP + k0 + 32);  ar1 = *(const u16x8*)(aP + k0 + 40);
            br0 = *(const u16x8*)(bP + k0 + 32);  br1 = *(const u16x8*)(bP + k0 + 40);
        }
        // compute
        bf16x8 af[4], bfr[4];
#pragma unroll
        for (int i = 0; i < 4; ++i) {
            af[i]  = *(const bf16x8*)&As[buf][(wm + i * 16 + r16) * RS + qd * 8];
            bfr[i] = *(const bf16x8*)&Bs[buf][(wn + i * 16 + r16) * RS + qd * 8];
        }
#pragma unroll
        for (int i = 0; i < 4; ++i)
#pragma unroll
            for (int j = 0; j < 4; ++j)
                acc[i][j] = __builtin_amdgcn_mfma_f32_16x16x32_bf16(af[i], bfr[j], acc[i][j], 0, 0, 0);
    }

    const int sel = n0 < 768 ? 0 : (n0 < 1536 ? 1 : 2);
    const float* bias = sel == 0 ? bq : (sel == 1 ? bk : bv);
    const float scale = sel == 0 ? QSCALE : 1.0f;
    const int nbase = n0 - sel * 768;

#pragma unroll
    for (int j = 0; j < 4; ++j) {
        const int ncol = nbase + wn + j * 16 + r16;
        const float bvv = bias[ncol];
#pragma unroll
        for (int i = 0; i < 4; ++i) {
            if (sel == 2) {
                const int h = ncol >> 6, d = ncol & 63;
                const int mb = m0 + wm + i * 16 + qd * 4;
                const int bb = mb >> 11, npb = mb & 2047;
                __bf16 pk[4];
#pragma unroll
                for (int rr = 0; rr < 4; ++rr) pk[rr] = (__bf16)(acc[i][j][rr] + bvv);
                *(bf16x4*)&Vt[(((size_t)(bb * NH + h)) * DK + d) * S_LEN + npb] = *(bf16x4*)pk;
            } else {
#pragma unroll
                for (int rr = 0; rr < 4; ++rr) {
                    const int m = m0 + wm + i * 16 + qd * 4 + rr;
                    const float v = (acc[i][j][rr] + bvv) * scale;
                    if (sel == 0) st_bf(&Qb[(size_t)m * D_MODEL + ncol], v);
                    else          st_bf(&Kb[(size_t)m * D_MODEL + ncol], v);
                }
            }
        }
    }
}

// ---------------------------------------------------------------------------
// GEMM 128x128 tile, BK=32 dbuf reg-prefetch, one barrier/iter.
// mode 1: bf16; 2: relu+bf16.
// ---------------------------------------------------------------------------
__global__ __launch_bounds__(256, 3)
void gemm_bt_k(const u16* __restrict__ A, const u16* __restrict__ Bt,
               const float* __restrict__ bias, u16* __restrict__ Cout,
               int M, int N, int K, int mode) {
    __shared__ __align__(16) u16 As[2][128 * RS];
    __shared__ __align__(16) u16 Bs[2][128 * RS];
    const int tid = threadIdx.x;
    const int lane = tid & 63, w = tid >> 6;
    const int r16 = lane & 15, qd = lane >> 4;
    const int m0 = blockIdx.x * 128, n0 = blockIdx.y * 128;
    const int wm = (w & 1) << 6, wn = (w >> 1) << 6;

    f32x4 acc[4][4] = {};

    const int srow = tid >> 1, scol = (tid & 1) << 4;
    const u16* aP = A  + (size_t)(m0 + srow) * K + scol;
    const u16* bP = Bt + (size_t)(n0 + srow) * K + scol;
    const int lds_off = srow * RS + scol;

    u16x8 ar0 = *(const u16x8*)(aP);     u16x8 ar1 = *(const u16x8*)(aP + 8);
    u16x8 br0 = *(const u16x8*)(bP);     u16x8 br1 = *(const u16x8*)(bP + 8);

    for (int k0 = 0, it = 0; k0 < K; k0 += 32, ++it) {
        const int buf = it & 1;
        *(u16x8*)&As[buf][lds_off]     = ar0;
        *(u16x8*)&As[buf][lds_off + 8] = ar1;
        *(u16x8*)&Bs[buf][lds_off]     = br0;
        *(u16x8*)&Bs[buf][lds_off + 8] = br1;
        __syncthreads();
        if (k0 + 32 < K) {
            ar0 = *(const u16x8*)(aP + k0 + 32);  ar1 = *(const u16x8*)(aP + k0 + 40);
            br0 = *(const u16x8*)(bP + k0 + 32);  br1 = *(const u16x8*)(bP + k0 + 40);
        }
        bf16x8 af[4], bfr[4];
#pragma unroll
        for (int i = 0; i < 4; ++i) {
            af[i]  = *(const bf16x8*)&As[buf][(wm + i * 16 + r16) * RS + qd * 8];
            bfr[i] = *(const bf16x8*)&Bs[buf][(wn + i * 16 + r16) * RS + qd * 8];
        }
#pragma unroll
        for (int i = 0; i < 4; ++i)
#pragma unroll
            for (int j = 0; j < 4; ++j)
                acc[i][j] = __builtin_amdgcn_mfma_f32_16x16x32_bf16(af[i], bfr[j], acc[i][j], 0, 0, 0);
    }

#pragma unroll
    for (int j = 0; j < 4; ++j) {
        const int n = n0 + wn + j * 16 + r16;
        const float bv = bias ? bias[n] : 0.0f;
#pragma unroll
        for (int i = 0; i < 4; ++i) {
#pragma unroll
            for (int rr = 0; rr < 4; ++rr) {
                const int m = m0 + wm + i * 16 + qd * 4 + rr;
                float v = acc[i][j][rr] + bv;
                if (mode == 2) v = fmaxf(v, 0.0f);
                st_bf(&Cout[(size_t)m * N + n], v);
            }
        }
    }
}

// ---------------------------------------------------------------------------
// GEMM 64x128 tile, BK=32 dbuf reg-prefetch, one barrier/iter.
// mode 1: bf16; mode 3: bf16 + residual add.
// ---------------------------------------------------------------------------
__global__ __launch_bounds__(256, 4)
void gemm_bt64_k(const u16* __restrict__ A, const u16* __restrict__ Bt,
                 const float* __restrict__ bias, const u16* __restrict__ resid,
                 u16* __restrict__ Cout, int M, int N, int K, int mode) {
    __shared__ __align__(16) u16 As[2][64 * RS];     // 10 KB
    __shared__ __align__(16) u16 Bs[2][128 * RS];    // 20 KB
    const int tid = threadIdx.x;
    const int lane = tid & 63, w = tid >> 6;
    const int r16 = lane & 15, qd = lane >> 4;
    const int m0 = blockIdx.x * 64, n0 = blockIdx.y * 128;
    const int wm = (w & 1) << 5, wn = (w >> 1) << 6;

    f32x4 acc[2][4] = {};

    const int arow = tid >> 2, acol = (tid & 3) << 3;    // 64 rows x {0,8,16,24}
    const int brow = tid >> 1, bcol = (tid & 1) << 4;    // 128 rows x {0,16}
    const u16* aP = A  + (size_t)(m0 + arow) * K + acol;
    const u16* bP = Bt + (size_t)(n0 + brow) * K + bcol;
    const int aoff = arow * RS + acol;
    const int boff = brow * RS + bcol;

    u16x8 ar0 = *(const u16x8*)(aP);
    u16x8 br0 = *(const u16x8*)(bP);     u16x8 br1 = *(const u16x8*)(bP + 8);

    for (int k0 = 0, it = 0; k0 < K; k0 += 32, ++it) {
        const int buf = it & 1;
        *(u16x8*)&As[buf][aoff]     = ar0;
        *(u16x8*)&Bs[buf][boff]     = br0;
        *(u16x8*)&Bs[buf][boff + 8] = br1;
        __syncthreads();
        if (k0 + 32 < K) {
            ar0 = *(const u16x8*)(aP + k0 + 32);
            br0 = *(const u16x8*)(bP + k0 + 32);  br1 = *(const u16x8*)(bP + k0 + 40);
        }
        bf16x8 af[2], bfr[4];
#pragma unroll
        for (int i = 0; i < 2; ++i)
            af[i] = *(const bf16x8*)&As[buf][(wm + i * 16 + r16) * RS + qd * 8];
#pragma unroll
        for (int j = 0; j < 4; ++j)
            bfr[j] = *(const bf16x8*)&Bs[buf][(wn + j * 16 + r16) * RS + qd * 8];
#pragma unroll
        for (int i = 0; i < 2; ++i)
#pragma unroll
            for (int j = 0; j < 4; ++j)
                acc[i][j] = __builtin_amdgcn_mfma_f32_16x16x32_bf16(af[i], bfr[j], acc[i][j], 0, 0, 0);
    }

#pragma unroll
    for (int j = 0; j < 4; ++j) {
        const int n = n0 + wn + j * 16 + r16;
        const float bv = bias ? bias[n] : 0.0f;
#pragma unroll
        for (int i = 0; i < 2; ++i) {
#pragma unroll
            for (int rr = 0; rr < 4; ++rr) {
                const int m = m0 + wm + i * 16 + qd * 4 + rr;
                float v = acc[i][j][rr] + bv;
                if (mode == 3) v += bf2f(resid[(size_t)m * N + n]);
                st_bf(&Cout[(size_t)m * N + n], v);
            }
        }
    }
}

// ---------------------------------------------------------------------------
// Flash attention v5 (unchanged from r6/r7). 128 q-rows/block, mask in
// acc-init, max-free softmax. grid (16,12,4)=768 = 3 blk/CU.
// ---------------------------------------------------------------------------
#define TS 72   // attn LDS row stride (u16)

__global__ __launch_bounds__(256, 3)
void attn_k(const u16* __restrict__ Qg, const u16* __restrict__ Kg,
            const u16* __restrict__ Vtg, const float* __restrict__ maskg,
            u16* __restrict__ Og) {
    const int tid = threadIdx.x, lane = tid & 63, w = tid >> 6;
    const int r16 = lane & 15, qd = lane >> 4;
    const int q0 = blockIdx.x * 128;
    const int h = blockIdx.y, b = blockIdx.z;

    __shared__ __align__(16) u16 Ks[64 * TS];
    __shared__ __align__(16) u16 Vts[64 * TS];
    __shared__ __align__(16) u16 Ps[128 * TS];

    bf16x8 qa[2][2];
#pragma unroll
    for (int mt = 0; mt < 2; ++mt)
#pragma unroll
        for (int ks = 0; ks < 2; ++ks)
            qa[mt][ks] = *(const bf16x8*)(Qg +
                ((size_t)((b * S_LEN + q0 + w * 32 + mt * 16 + r16) * NH + h)) * DK +
                ks * 32 + qd * 8);

    const int srow = tid >> 3, sc = (tid & 7) << 3;
    u16x8 kreg[2], vreg[2];
#pragma unroll
    for (int it = 0; it < 2; ++it) {
        const int row = srow + it * 32;
        kreg[it] = *(const u16x8*)(Kg + ((size_t)((b * S_LEN + row) * NH + h)) * DK + sc);
        vreg[it] = *(const u16x8*)(Vtg + (((size_t)(b * NH + h)) * DK + row) * S_LEN + sc);
    }

    float l_i[2] = {0.0f, 0.0f};
    f32x4 Oacc[2][4] = {};

    for (int kt = 0; kt < S_LEN / 64; ++kt) {
        const int ks0 = kt * 64;

#pragma unroll
        for (int it = 0; it < 2; ++it) {
            const int row = srow + it * 32;
            *(u16x8*)&Ks[row * TS + sc]  = kreg[it];
            *(u16x8*)&Vts[row * TS + sc] = vreg[it];
        }

        float4 mrow[4];
#pragma unroll
        for (int nt = 0; nt < 4; ++nt) {
            const float4 mm = ((const float4*)(maskg + (size_t)b * S_LEN + ks0))[nt * 4 + qd];
            mrow[nt].x = mm.x * MSCALE; mrow[nt].y = mm.y * MSCALE;
            mrow[nt].z = mm.z * MSCALE; mrow[nt].w = mm.w * MSCALE;
        }
        __syncthreads();

        if (kt + 1 < S_LEN / 64) {
            const int ns0 = ks0 + 64;
#pragma unroll
            for (int it = 0; it < 2; ++it) {
                const int row = srow + it * 32;
                kreg[it] = *(const u16x8*)(Kg + ((size_t)((b * S_LEN + ns0 + row) * NH + h)) * DK + sc);
                vreg[it] = *(const u16x8*)(Vtg + (((size_t)(b * NH + h)) * DK + row) * S_LEN + ns0 + sc);
            }
        }

        f32x4 sa[2][4];
#pragma unroll
        for (int mt = 0; mt < 2; ++mt)
#pragma unroll
            for (int nt = 0; nt < 4; ++nt) {
                sa[mt][nt][0] = mrow[nt].x; sa[mt][nt][1] = mrow[nt].y;
                sa[mt][nt][2] = mrow[nt].z; sa[mt][nt][3] = mrow[nt].w;
            }
#pragma unroll
        for (int ks = 0; ks < 2; ++ks) {
            bf16x8 kb[4];
#pragma unroll
            for (int nt = 0; nt < 4; ++nt)
                kb[nt] = *(const bf16x8*)&Ks[(nt * 16 + r16) * TS + ks * 32 + qd * 8];
#pragma unroll
            for (int mt = 0; mt < 2; ++mt)
#pragma unroll
                for (int nt = 0; nt < 4; ++nt)
                    sa[mt][nt] = __builtin_amdgcn_mfma_f32_16x16x32_bf16(kb[nt], qa[mt][ks], sa[mt][nt], 0, 0, 0);
        }

#pragma unroll
        for (int mt = 0; mt < 2; ++mt) {
            float rsum = 0.0f;
#pragma unroll
            for (int nt = 0; nt < 4; ++nt) {
                sa[mt][nt][0] = __builtin_amdgcn_exp2f(sa[mt][nt][0]);
                sa[mt][nt][1] = __builtin_amdgcn_exp2f(sa[mt][nt][1]);
                sa[mt][nt][2] = __builtin_amdgcn_exp2f(sa[mt][nt][2]);
                sa[mt][nt][3] = __builtin_amdgcn_exp2f(sa[mt][nt][3]);
                rsum += sa[mt][nt][0] + sa[mt][nt][1] + sa[mt][nt][2] + sa[mt][nt][3];
            }
            rsum += __shfl_xor(rsum, 16);
            rsum += __shfl_xor(rsum, 32);
            l_i[mt] += rsum;
        }

#pragma unroll
        for (int mt = 0; mt < 2; ++mt)
#pragma unroll
            for (int nt = 0; nt < 4; ++nt) {
                __bf16 pk[4];
#pragma unroll
                for (int rr = 0; rr < 4; ++rr) pk[rr] = (__bf16)sa[mt][nt][rr];
                *(bf16x4*)&Ps[(w * 32 + mt * 16 + r16) * TS + nt * 16 + qd * 4] = *(bf16x4*)pk;
            }

#pragma unroll
        for (int ks = 0; ks < 2; ++ks) {
            bf16x8 pa[2], vb[4];
#pragma unroll
            for (int mt = 0; mt < 2; ++mt)
                pa[mt] = *(const bf16x8*)&Ps[(w * 32 + mt * 16 + r16) * TS + ks * 32 + qd * 8];
#pragma unroll
            for (int vt = 0; vt < 4; ++vt)
                vb[vt] = *(const bf16x8*)&Vts[(vt * 16 + r16) * TS + ks * 32 + qd * 8];
#pragma unroll
            for (int mt = 0; mt < 2; ++mt)
#pragma unroll
                for (int vt = 0; vt < 4; ++vt)
                    Oacc[mt][vt] = __builtin_amdgcn_mfma_f32_16x16x32_bf16(pa[mt], vb[vt], Oacc[mt][vt], 0, 0, 0);
        }
        __syncthreads();
    }

#pragma unroll
    for (int mt = 0; mt < 2; ++mt) {
        const float linv = 1.0f / l_i[mt];
#pragma unroll
        for (int rr = 0; rr < 4; ++rr) {
            const float lr = __shfl(linv, qd * 4 + rr);
            const int qrow = q0 + w * 32 + mt * 16 + qd * 4 + rr;
#pragma unroll
            for (int vt = 0; vt < 4; ++vt)
                st_bf(&Og[((size_t)((b * S_LEN + qrow) * NH + h)) * DK + vt * 16 + r16],
                      Oacc[mt][vt][rr] * lr);
        }
    }
}

// ---------------------------------------------------------------------------
// LayerNorm over D=768, single bf16 input (residual already summed).
// ---------------------------------------------------------------------------
__global__ __launch_bounds__(256, 4)
void ln_k(const u16* __restrict__ rb, const float* __restrict__ gamma,
          const float* __restrict__ beta, u16* __restrict__ outb,
          float* __restrict__ outf) {
    const int row = blockIdx.x, tid = threadIdx.x;
    const int lane = tid & 63, w = tid >> 6;
    __shared__ float redS[4], redS2[4];
    const size_t base = (size_t)row * D_MODEL;
    float h[3], s = 0.0f, s2 = 0.0f;
#pragma unroll
    for (int i = 0; i < 3; ++i) {
        const int c = i * 256 + tid;
        const float v = bf2f(rb[base + c]);
        h[i] = v; s += v; s2 += v * v;
    }
#pragma unroll
    for (int off = 32; off >= 1; off >>= 1) { s += __shfl_xor(s, off); s2 += __shfl_xor(s2, off); }
    if (lane == 0) { redS[w] = s; redS2[w] = s2; }
    __syncthreads();
    s  = redS[0] + redS[1] + redS[2] + redS[3];
    s2 = redS2[0] + redS2[1] + redS2[2] + redS2[3];
    const float mu  = s * (1.0f / D_MODEL);
    const float var = s2 * (1.0f / D_MODEL) - mu * mu;
    const float rstd = rsqrtf(var + 1e-3f);
#pragma unroll
    for (int i = 0; i < 3; ++i) {
        const int c = i * 256 + tid;
        const float o = (h[i] - mu) * rstd * gamma[c] + beta[c];
        if (outb) st_bf(&outb[base + c], o);
        if (outf) outf[base + c] = o;
    }
}

// ---------------------------------------------------------------------------
extern "C" void kernel_launch(void* const* d_in, const int* in_sizes, int n_in,
                              void* d_out, int out_size, void* d_ws, size_t ws_size,
                              hipStream_t stream) {
    (void)in_sizes; (void)n_in; (void)out_size; (void)ws_size;
    const float* x    = (const float*)d_in[0];
    const float* mask = (const float*)d_in[1];
    const float* Wq = (const float*)d_in[2];  const float* bq  = (const float*)d_in[3];
    const float* Wk = (const float*)d_in[4];  const float* bk  = (const float*)d_in[5];
    const float* Wv = (const float*)d_in[6];  const float* bv  = (const float*)d_in[7];
    const float* Wo = (const float*)d_in[8];  const float* bo  = (const float*)d_in[9];
    const float* W1 = (const float*)d_in[10]; const float* b1  = (const float*)d_in[11];
    const float* W2 = (const float*)d_in[12]; const float* b2  = (const float*)d_in[13];
    const float* g1 = (const float*)d_in[14]; const float* be1 = (const float*)d_in[15];
    const float* g2 = (const float*)d_in[16]; const float* be2 = (const float*)d_in[17];

    char* ws = (char*)d_ws;
    u16* xb     = (u16*)(ws + 0);            // 12,582,912
    u16* WqkvT  = (u16*)(ws + 12582912);     //  3,538,944
    u16* WoT    = (u16*)(ws + 16121856);     //  1,179,648
    u16* W1T    = (u16*)(ws + 17301504);     //  3,145,728
    u16* W2T    = (u16*)(ws + 20447232);     //  3,145,728
    u16* Qb     = (u16*)(ws + 23592960);     // 12,582,912
    u16* Kb     = (u16*)(ws + 36175872);     // 12,582,912
    u16* Vtg    = (u16*)(ws + 48758784);     // 12,582,912 [B,H,Dk,S]
    u16* Ab     = (u16*)(ws + 61341696);     // 12,582,912
    u16* R1b    = (u16*)(ws + 73924608);     // 12,582,912 (resid1 = x + attnY)
    u16* X1b    = (u16*)(ws + 86507520);     // 12,582,912 (end ~99 MB)
    u16* H1b    = (u16*)(ws + 23592960);     // reuse Qb/Kb/Vtg (dead after attn)
    u16* R2b    = (u16*)(ws + 73924608);     // reuse R1b (dead after LN1)

    const dim3 blk(256);

    // 0. fused prep: x->bf16 + all 6 weight transposes
    prep_k<<<dim3(11520), blk, 0, stream>>>(x, Wq, Wk, Wv, Wo, W1, W2,
                                            xb, WqkvT, WoT, W1T, W2T);

    // 1. fused QKV projection (V pre-transposed), dbuf staging
    qkv_gemm_k<<<dim3(64, 18), blk, 0, stream>>>(xb, WqkvT, bq, bk, bv, Qb, Kb, Vtg);

    // 2. flash attention v5
    attn_k<<<dim3(16, NH, 4), blk, 0, stream>>>(Qb, Kb, Vtg, mask, Ab);

    // 3. output projection + residual: R1 = attn@Wo + bo + x
    gemm_bt64_k<<<dim3(128, 6), blk, 0, stream>>>(Ab, WoT, bo, xb, R1b,
                                                  M_TOK, D_MODEL, D_MODEL, 3);

    // 4. LN1: x1 = LN(R1) -> bf16
    ln_k<<<dim3(M_TOK), blk, 0, stream>>>(R1b, g1, be1, X1b, nullptr);

    // 5. FF1: H1 = relu(x1@W1 + b1) bf16
    gemm_bt_k<<<dim3(64, 16), blk, 0, stream>>>(X1b, W1T, b1, H1b, M_TOK, D_FF, D_MODEL, 2);

    // 6. FF2 + residual: R2 = H1@W2 + b2 + x1
    gemm_bt64_k<<<dim3(128, 6), blk, 0, stream>>>(H1b, W2T, b2, X1b, R2b,
                                                  M_TOK, D_MODEL, D_FF, 3);

    // 7. LN2: out = LN(R2) fp32 -> d_out
    ln_k<<<dim3(M_TOK), blk, 0, stream>>>(R2b, g2, be2, nullptr, (float*)d_out);
}

// Round 9
// 360.240 us; speedup vs baseline: 1.0330x; 1.0330x over previous
//
#include <hip/hip_runtime.h>

// ---------------------------------------------------------------------------
// EncoderLayer on MI355X (gfx950). fp32 in/out, bf16 MFMA compute inside.
// B=4 S=2048 D=768 H=12 Dk=64 Dff=2048, M = B*S = 8192 tokens.
//
// Round 9: GEMMs reverted to r6's measured-best structure (BK=64 two-panel
// global_load_lds, (256,2)/(256,3)); residual fusion kept (mode 3);
// XCD-aware attention block swizzle (each XCD owns whole (h,b) K/V sets).
// ---------------------------------------------------------------------------

typedef unsigned short u16;
typedef __bf16 bf16x8 __attribute__((ext_vector_type(8)));
typedef __bf16 bf16x4 __attribute__((ext_vector_type(4)));
typedef unsigned short u16x8 __attribute__((ext_vector_type(8)));
typedef float f32x4 __attribute__((ext_vector_type(4)));

#define D_MODEL 768
#define D_FF    2048
#define NH      12
#define DK      64
#define S_LEN   2048
#define M_TOK   8192

#define QSCALE   0.18033688011112042f   /* 0.125 * log2(e) */
#define MSCALE  -1.4426950408889634e9f  /* -1e9 * log2(e)  */

__device__ __forceinline__ float bf2f(u16 v) {
    union { unsigned u; float f; } c; c.u = ((unsigned)v) << 16; return c.f;
}
__device__ __forceinline__ void st_bf(u16* p, float v) { *(__bf16*)p = (__bf16)v; }

// async global->LDS, 16B/lane; LDS dest must be wave-uniform base + lane*16.
__device__ __forceinline__ void gload_lds16(const void* g, void* l) {
    __builtin_amdgcn_global_load_lds(
        (const __attribute__((address_space(1))) void*)g,
        (__attribute__((address_space(3))) void*)l, 16, 0, 0);
}

// ---------------------------------------------------------------------------
// Fused prep: blocks [0,2304) = 4x 768x768 transposes; [2304,3840) = W1;
// [3840,5376) = W2; [5376,11520) = x fp32->bf16.
// ---------------------------------------------------------------------------
__global__ __launch_bounds__(256)
void prep_k(const float* __restrict__ x, const float* __restrict__ Wq,
            const float* __restrict__ Wk, const float* __restrict__ Wv,
            const float* __restrict__ Wo, const float* __restrict__ W1,
            const float* __restrict__ W2, u16* __restrict__ xb,
            u16* __restrict__ WqkvT, u16* __restrict__ WoT,
            u16* __restrict__ W1T, u16* __restrict__ W2T) {
    __shared__ float t[32][33];
    const int id = blockIdx.x, tid = threadIdx.x;
    if (id >= 5376) {               // ---- x convert ----
        const int i = ((id - 5376) * 256 + tid) * 4;
        const float4 v = *(const float4*)(x + i);
        __bf16 o[4] = {(__bf16)v.x, (__bf16)v.y, (__bf16)v.z, (__bf16)v.w};
        *(bf16x4*)(xb + i) = *(bf16x4*)o;
        return;
    }
    const float* in; u16* out; int R, C, bx, by;
    if (id < 2304) {                // ---- Wq/Wk/Wv/Wo 768x768 ----
        const int z = id / 576, r = id % 576;
        in = z == 0 ? Wq : (z == 1 ? Wk : (z == 2 ? Wv : Wo));
        out = z == 3 ? WoT : WqkvT + z * 768 * 768;
        R = 768; C = 768; bx = (r % 24) * 32; by = (r / 24) * 32;
    } else if (id < 3840) {         // ---- W1 [768,2048] -> [2048,768] ----
        const int r = id - 2304;
        in = W1; out = W1T; R = 768; C = 2048;
        bx = (r % 64) * 32; by = (r / 64) * 32;
    } else {                        // ---- W2 [2048,768] -> [768,2048] ----
        const int r = id - 3840;
        in = W2; out = W2T; R = 2048; C = 768;
        bx = (r % 24) * 32; by = (r / 24) * 32;
    }
    const int tx = tid & 31, ty = tid >> 5;
#pragma unroll
    for (int i = 0; i < 32; i += 8)
        t[ty + i][tx] = in[(size_t)(by + ty + i) * C + bx + tx];
    __syncthreads();
#pragma unroll
    for (int i = 0; i < 32; i += 8)
        st_bf(&out[(size_t)(bx + ty + i) * R + by + tx], t[tx][ty + i]);
}

// ---------------------------------------------------------------------------
// Fused QKV GEMM, 128x128 tile, BK=64 (two BK=32 panels via global_load_lds).
// n in [0,768): Q*QSCALE -> Qb; [768,1536): K -> Kb; [1536,2304): V -> Vt
// (pre-transposed [B,H,Dk,S]). r6's measured-best structure.
// ---------------------------------------------------------------------------
__global__ __launch_bounds__(256, 2)
void qkv_gemm_k(const u16* __restrict__ A, const u16* __restrict__ Bt,
                const float* __restrict__ bq, const float* __restrict__ bk,
                const float* __restrict__ bv, u16* __restrict__ Qb,
                u16* __restrict__ Kb, u16* __restrict__ Vt) {
    __shared__ __align__(16) u16 As[2][128 * 32];
    __shared__ __align__(16) u16 Bs[2][128 * 32];
    const int tid = threadIdx.x;
    const int lane = tid & 63, w = tid >> 6;
    const int r16 = lane & 15, qd = lane >> 4;
    const int m0 = blockIdx.x * 128, n0 = blockIdx.y * 128;
    const int wm = (w & 1) << 6, wn = (w >> 1) << 6;
    const int K = D_MODEL;

    f32x4 acc[4][4] = {};

    const u16* aP[2]; const u16* bP[2]; int f8[2];
#pragma unroll
    for (int it = 0; it < 2; ++it) {
        const int f = it * 256 + tid;
        const int row = f >> 2, kc = (f & 3) << 3;
        aP[it] = A  + (size_t)(m0 + row) * K + kc;
        bP[it] = Bt + (size_t)(n0 + row) * K + kc;
        f8[it] = f * 8;
    }

    for (int k0 = 0; k0 < K; k0 += 64) {
#pragma unroll
        for (int p = 0; p < 2; ++p)
#pragma unroll
            for (int it = 0; it < 2; ++it) {
                gload_lds16(aP[it] + k0 + p * 32, &As[p][f8[it]]);
                gload_lds16(bP[it] + k0 + p * 32, &Bs[p][f8[it]]);
            }
        __syncthreads();
#pragma unroll
        for (int p = 0; p < 2; ++p) {
            bf16x8 af[4], bfr[4];
#pragma unroll
            for (int i = 0; i < 4; ++i) {
                af[i]  = *(const bf16x8*)&As[p][(wm + i * 16 + r16) * 32 + qd * 8];
                bfr[i] = *(const bf16x8*)&Bs[p][(wn + i * 16 + r16) * 32 + qd * 8];
            }
#pragma unroll
            for (int i = 0; i < 4; ++i)
#pragma unroll
                for (int j = 0; j < 4; ++j)
                    acc[i][j] = __builtin_amdgcn_mfma_f32_16x16x32_bf16(af[i], bfr[j], acc[i][j], 0, 0, 0);
        }
        __syncthreads();
    }

    const int sel = n0 < 768 ? 0 : (n0 < 1536 ? 1 : 2);
    const float* bias = sel == 0 ? bq : (sel == 1 ? bk : bv);
    const float scale = sel == 0 ? QSCALE : 1.0f;
    const int nbase = n0 - sel * 768;

#pragma unroll
    for (int j = 0; j < 4; ++j) {
        const int ncol = nbase + wn + j * 16 + r16;
        const float bvv = bias[ncol];
#pragma unroll
        for (int i = 0; i < 4; ++i) {
            if (sel == 2) {
                const int h = ncol >> 6, d = ncol & 63;
                const int mb = m0 + wm + i * 16 + qd * 4;
                const int bb = mb >> 11, npb = mb & 2047;
                __bf16 pk[4];
#pragma unroll
                for (int rr = 0; rr < 4; ++rr) pk[rr] = (__bf16)(acc[i][j][rr] + bvv);
                *(bf16x4*)&Vt[(((size_t)(bb * NH + h)) * DK + d) * S_LEN + npb] = *(bf16x4*)pk;
            } else {
#pragma unroll
                for (int rr = 0; rr < 4; ++rr) {
                    const int m = m0 + wm + i * 16 + qd * 4 + rr;
                    const float v = (acc[i][j][rr] + bvv) * scale;
                    if (sel == 0) st_bf(&Qb[(size_t)m * D_MODEL + ncol], v);
                    else          st_bf(&Kb[(size_t)m * D_MODEL + ncol], v);
                }
            }
        }
    }
}

// ---------------------------------------------------------------------------
// GEMM 128x128 tile, BK=64 (two panels, global_load_lds), (256,2).
// mode 1: bf16; 2: relu+bf16.
// ---------------------------------------------------------------------------
__global__ __launch_bounds__(256, 2)
void gemm_bt_k(const u16* __restrict__ A, const u16* __restrict__ Bt,
               const float* __restrict__ bias, u16* __restrict__ Cout,
               int M, int N, int K, int mode) {
    __shared__ __align__(16) u16 As[2][128 * 32];
    __shared__ __align__(16) u16 Bs[2][128 * 32];
    const int tid = threadIdx.x;
    const int lane = tid & 63, w = tid >> 6;
    const int r16 = lane & 15, qd = lane >> 4;
    const int m0 = blockIdx.x * 128, n0 = blockIdx.y * 128;
    const int wm = (w & 1) << 6, wn = (w >> 1) << 6;

    f32x4 acc[4][4] = {};

    const u16* aP[2]; const u16* bP[2]; int f8[2];
#pragma unroll
    for (int it = 0; it < 2; ++it) {
        const int f = it * 256 + tid;
        const int row = f >> 2, kc = (f & 3) << 3;
        aP[it] = A  + (size_t)(m0 + row) * K + kc;
        bP[it] = Bt + (size_t)(n0 + row) * K + kc;
        f8[it] = f * 8;
    }

    for (int k0 = 0; k0 < K; k0 += 64) {
#pragma unroll
        for (int p = 0; p < 2; ++p)
#pragma unroll
            for (int it = 0; it < 2; ++it) {
                gload_lds16(aP[it] + k0 + p * 32, &As[p][f8[it]]);
                gload_lds16(bP[it] + k0 + p * 32, &Bs[p][f8[it]]);
            }
        __syncthreads();
#pragma unroll
        for (int p = 0; p < 2; ++p) {
            bf16x8 af[4], bfr[4];
#pragma unroll
            for (int i = 0; i < 4; ++i) {
                af[i]  = *(const bf16x8*)&As[p][(wm + i * 16 + r16) * 32 + qd * 8];
                bfr[i] = *(const bf16x8*)&Bs[p][(wn + i * 16 + r16) * 32 + qd * 8];
            }
#pragma unroll
            for (int i = 0; i < 4; ++i)
#pragma unroll
                for (int j = 0; j < 4; ++j)
                    acc[i][j] = __builtin_amdgcn_mfma_f32_16x16x32_bf16(af[i], bfr[j], acc[i][j], 0, 0, 0);
        }
        __syncthreads();
    }

#pragma unroll
    for (int j = 0; j < 4; ++j) {
        const int n = n0 + wn + j * 16 + r16;
        const float bv = bias ? bias[n] : 0.0f;
#pragma unroll
        for (int i = 0; i < 4; ++i) {
#pragma unroll
            for (int rr = 0; rr < 4; ++rr) {
                const int m = m0 + wm + i * 16 + qd * 4 + rr;
                float v = acc[i][j][rr] + bv;
                if (mode == 2) v = fmaxf(v, 0.0f);
                st_bf(&Cout[(size_t)m * N + n], v);
            }
        }
    }
}

// ---------------------------------------------------------------------------
// GEMM 64x128 tile, BK=64 (two panels, global_load_lds), (256,3).
// mode 1: bf16; mode 3: bf16 + residual add.
// ---------------------------------------------------------------------------
__global__ __launch_bounds__(256, 3)
void gemm_bt64_k(const u16* __restrict__ A, const u16* __restrict__ Bt,
                 const float* __restrict__ bias, const u16* __restrict__ resid,
                 u16* __restrict__ Cout, int M, int N, int K, int mode) {
    __shared__ __align__(16) u16 As[2][64 * 32];
    __shared__ __align__(16) u16 Bs[2][128 * 32];
    const int tid = threadIdx.x;
    const int lane = tid & 63, w = tid >> 6;
    const int r16 = lane & 15, qd = lane >> 4;
    const int m0 = blockIdx.x * 64, n0 = blockIdx.y * 128;
    const int wm = (w & 1) << 5, wn = (w >> 1) << 6;

    f32x4 acc[2][4] = {};

    const int arow = tid >> 2, akc = (tid & 3) << 3;
    const u16* aP = A + (size_t)(m0 + arow) * K + akc;
    const u16* bP[2]; int f8[2];
#pragma unroll
    for (int it = 0; it < 2; ++it) {
        const int f = it * 256 + tid;
        const int row = f >> 2, kc = (f & 3) << 3;
        bP[it] = Bt + (size_t)(n0 + row) * K + kc;
        f8[it] = f * 8;
    }

    for (int k0 = 0; k0 < K; k0 += 64) {
#pragma unroll
        for (int p = 0; p < 2; ++p) {
            gload_lds16(aP + k0 + p * 32, &As[p][tid * 8]);
#pragma unroll
            for (int it = 0; it < 2; ++it)
                gload_lds16(bP[it] + k0 + p * 32, &Bs[p][f8[it]]);
        }
        __syncthreads();
#pragma unroll
        for (int p = 0; p < 2; ++p) {
            bf16x8 af[2], bfr[4];
#pragma unroll
            for (int i = 0; i < 2; ++i)
                af[i] = *(const bf16x8*)&As[p][(wm + i * 16 + r16) * 32 + qd * 8];
#pragma unroll
            for (int j = 0; j < 4; ++j)
                bfr[j] = *(const bf16x8*)&Bs[p][(wn + j * 16 + r16) * 32 + qd * 8];
#pragma unroll
            for (int i = 0; i < 2; ++i)
#pragma unroll
                for (int j = 0; j < 4; ++j)
                    acc[i][j] = __builtin_amdgcn_mfma_f32_16x16x32_bf16(af[i], bfr[j], acc[i][j], 0, 0, 0);
        }
        __syncthreads();
    }

#pragma unroll
    for (int j = 0; j < 4; ++j) {
        const int n = n0 + wn + j * 16 + r16;
        const float bv = bias ? bias[n] : 0.0f;
#pragma unroll
        for (int i = 0; i < 2; ++i) {
#pragma unroll
            for (int rr = 0; rr < 4; ++rr) {
                const int m = m0 + wm + i * 16 + qd * 4 + rr;
                float v = acc[i][j][rr] + bv;
                if (mode == 3) v += bf2f(resid[(size_t)m * N + n]);
                st_bf(&Cout[(size_t)m * N + n], v);
            }
        }
    }
}

// ---------------------------------------------------------------------------
// Flash attention v6 = v5 + XCD-aware 1-D swizzle. 768 blocks; dispatch
// round-robins XCDs (id % 8), so give XCD g the 6 (h,b) pairs hb in
// [6g,6g+6), all 16 q-tiles each -> K/V L2-resident per XCD.
// ---------------------------------------------------------------------------
#define TS 72   // attn LDS row stride (u16)

__global__ __launch_bounds__(256, 3)
void attn_k(const u16* __restrict__ Qg, const u16* __restrict__ Kg,
            const u16* __restrict__ Vtg, const float* __restrict__ maskg,
            u16* __restrict__ Og) {
    const int tid = threadIdx.x, lane = tid & 63, w = tid >> 6;
    const int r16 = lane & 15, qd = lane >> 4;
    // ---- XCD swizzle: id%8 = XCD, each XCD owns whole (h,b) K/V sets ----
    const int flat = blockIdx.x;
    const int xcd = flat & 7, loc = flat >> 3;          // loc in [0,96)
    const int hb = xcd * 6 + (loc >> 4);                // [0,48)
    const int q0 = (loc & 15) * 128;
    const int h = hb >> 2, b = hb & 3;                  // hb = h*4 + b

    __shared__ __align__(16) u16 Ks[64 * TS];
    __shared__ __align__(16) u16 Vts[64 * TS];
    __shared__ __align__(16) u16 Ps[128 * TS];

    bf16x8 qa[2][2];
#pragma unroll
    for (int mt = 0; mt < 2; ++mt)
#pragma unroll
        for (int ks = 0; ks < 2; ++ks)
            qa[mt][ks] = *(const bf16x8*)(Qg +
                ((size_t)((b * S_LEN + q0 + w * 32 + mt * 16 + r16) * NH + h)) * DK +
                ks * 32 + qd * 8);

    const int srow = tid >> 3, sc = (tid & 7) << 3;
    u16x8 kreg[2], vreg[2];
#pragma unroll
    for (int it = 0; it < 2; ++it) {
        const int row = srow + it * 32;
        kreg[it] = *(const u16x8*)(Kg + ((size_t)((b * S_LEN + row) * NH + h)) * DK + sc);
        vreg[it] = *(const u16x8*)(Vtg + (((size_t)(b * NH + h)) * DK + row) * S_LEN + sc);
    }

    float l_i[2] = {0.0f, 0.0f};
    f32x4 Oacc[2][4] = {};

    for (int kt = 0; kt < S_LEN / 64; ++kt) {
        const int ks0 = kt * 64;

#pragma unroll
        for (int it = 0; it < 2; ++it) {
            const int row = srow + it * 32;
            *(u16x8*)&Ks[row * TS + sc]  = kreg[it];
            *(u16x8*)&Vts[row * TS + sc] = vreg[it];
        }

        float4 mrow[4];
#pragma unroll
        for (int nt = 0; nt < 4; ++nt) {
            const float4 mm = ((const float4*)(maskg + (size_t)b * S_LEN + ks0))[nt * 4 + qd];
            mrow[nt].x = mm.x * MSCALE; mrow[nt].y = mm.y * MSCALE;
            mrow[nt].z = mm.z * MSCALE; mrow[nt].w = mm.w * MSCALE;
        }
        __syncthreads();

        if (kt + 1 < S_LEN / 64) {
            const int ns0 = ks0 + 64;
#pragma unroll
            for (int it = 0; it < 2; ++it) {
                const int row = srow + it * 32;
                kreg[it] = *(const u16x8*)(Kg + ((size_t)((b * S_LEN + ns0 + row) * NH + h)) * DK + sc);
                vreg[it] = *(const u16x8*)(Vtg + (((size_t)(b * NH + h)) * DK + row) * S_LEN + ns0 + sc);
            }
        }

        f32x4 sa[2][4];
#pragma unroll
        for (int mt = 0; mt < 2; ++mt)
#pragma unroll
            for (int nt = 0; nt < 4; ++nt) {
                sa[mt][nt][0] = mrow[nt].x; sa[mt][nt][1] = mrow[nt].y;
                sa[mt][nt][2] = mrow[nt].z; sa[mt][nt][3] = mrow[nt].w;
            }
#pragma unroll
        for (int ks = 0; ks < 2; ++ks) {
            bf16x8 kb[4];
#pragma unroll
            for (int nt = 0; nt < 4; ++nt)
                kb[nt] = *(const bf16x8*)&Ks[(nt * 16 + r16) * TS + ks * 32 + qd * 8];
#pragma unroll
            for (int mt = 0; mt < 2; ++mt)
#pragma unroll
                for (int nt = 0; nt < 4; ++nt)
                    sa[mt][nt] = __builtin_amdgcn_mfma_f32_16x16x32_bf16(kb[nt], qa[mt][ks], sa[mt][nt], 0, 0, 0);
        }

#pragma unroll
        for (int mt = 0; mt < 2; ++mt) {
            float rsum = 0.0f;
#pragma unroll
            for (int nt = 0; nt < 4; ++nt) {
                sa[mt][nt][0] = __builtin_amdgcn_exp2f(sa[mt][nt][0]);
                sa[mt][nt][1] = __builtin_amdgcn_exp2f(sa[mt][nt][1]);
                sa[mt][nt][2] = __builtin_amdgcn_exp2f(sa[mt][nt][2]);
                sa[mt][nt][3] = __builtin_amdgcn_exp2f(sa[mt][nt][3]);
                rsum += sa[mt][nt][0] + sa[mt][nt][1] + sa[mt][nt][2] + sa[mt][nt][3];
            }
            rsum += __shfl_xor(rsum, 16);
            rsum += __shfl_xor(rsum, 32);
            l_i[mt] += rsum;
        }

#pragma unroll
        for (int mt = 0; mt < 2; ++mt)
#pragma unroll
            for (int nt = 0; nt < 4; ++nt) {
                __bf16 pk[4];
#pragma unroll
                for (int rr = 0; rr < 4; ++rr) pk[rr] = (__bf16)sa[mt][nt][rr];
                *(bf16x4*)&Ps[(w * 32 + mt * 16 + r16) * TS + nt * 16 + qd * 4] = *(bf16x4*)pk;
            }

#pragma unroll
        for (int ks = 0; ks < 2; ++ks) {
            bf16x8 pa[2], vb[4];
#pragma unroll
            for (int mt = 0; mt < 2; ++mt)
                pa[mt] = *(const bf16x8*)&Ps[(w * 32 + mt * 16 + r16) * TS + ks * 32 + qd * 8];
#pragma unroll
            for (int vt = 0; vt < 4; ++vt)
                vb[vt] = *(const bf16x8*)&Vts[(vt * 16 + r16) * TS + ks * 32 + qd * 8];
#pragma unroll
            for (int mt = 0; mt < 2; ++mt)
#pragma unroll
                for (int vt = 0; vt < 4; ++vt)
                    Oacc[mt][vt] = __builtin_amdgcn_mfma_f32_16x16x32_bf16(pa[mt], vb[vt], Oacc[mt][vt], 0, 0, 0);
        }
        __syncthreads();
    }

#pragma unroll
    for (int mt = 0; mt < 2; ++mt) {
        const float linv = 1.0f / l_i[mt];
#pragma unroll
        for (int rr = 0; rr < 4; ++rr) {
            const float lr = __shfl(linv, qd * 4 + rr);
            const int qrow = q0 + w * 32 + mt * 16 + qd * 4 + rr;
#pragma unroll
            for (int vt = 0; vt < 4; ++vt)
                st_bf(&Og[((size_t)((b * S_LEN + qrow) * NH + h)) * DK + vt * 16 + r16],
                      Oacc[mt][vt][rr] * lr);
        }
    }
}

// ---------------------------------------------------------------------------
// LayerNorm over D=768, single bf16 input (residual already summed).
// ---------------------------------------------------------------------------
__global__ __launch_bounds__(256, 4)
void ln_k(const u16* __restrict__ rb, const float* __restrict__ gamma,
          const float* __restrict__ beta, u16* __restrict__ outb,
          float* __restrict__ outf) {
    const int row = blockIdx.x, tid = threadIdx.x;
    const int lane = tid & 63, w = tid >> 6;
    __shared__ float redS[4], redS2[4];
    const size_t base = (size_t)row * D_MODEL;
    float h[3], s = 0.0f, s2 = 0.0f;
#pragma unroll
    for (int i = 0; i < 3; ++i) {
        const int c = i * 256 + tid;
        const float v = bf2f(rb[base + c]);
        h[i] = v; s += v; s2 += v * v;
    }
#pragma unroll
    for (int off = 32; off >= 1; off >>= 1) { s += __shfl_xor(s, off); s2 += __shfl_xor(s2, off); }
    if (lane == 0) { redS[w] = s; redS2[w] = s2; }
    __syncthreads();
    s  = redS[0] + redS[1] + redS[2] + redS[3];
    s2 = redS2[0] + redS2[1] + redS2[2] + redS2[3];
    const float mu  = s * (1.0f / D_MODEL);
    const float var = s2 * (1.0f / D_MODEL) - mu * mu;
    const float rstd = rsqrtf(var + 1e-3f);
#pragma unroll
    for (int i = 0; i < 3; ++i) {
        const int c = i * 256 + tid;
        const float o = (h[i] - mu) * rstd * gamma[c] + beta[c];
        if (outb) st_bf(&outb[base + c], o);
        if (outf) outf[base + c] = o;
    }
}

// ---------------------------------------------------------------------------
extern "C" void kernel_launch(void* const* d_in, const int* in_sizes, int n_in,
                              void* d_out, int out_size, void* d_ws, size_t ws_size,
                              hipStream_t stream) {
    (void)in_sizes; (void)n_in; (void)out_size; (void)ws_size;
    const float* x    = (const float*)d_in[0];
    const float* mask = (const float*)d_in[1];
    const float* Wq = (const float*)d_in[2];  const float* bq  = (const float*)d_in[3];
    const float* Wk = (const float*)d_in[4];  const float* bk  = (const float*)d_in[5];
    const float* Wv = (const float*)d_in[6];  const float* bv  = (const float*)d_in[7];
    const float* Wo = (const float*)d_in[8];  const float* bo  = (const float*)d_in[9];
    const float* W1 = (const float*)d_in[10]; const float* b1  = (const float*)d_in[11];
    const float* W2 = (const float*)d_in[12]; const float* b2  = (const float*)d_in[13];
    const float* g1 = (const float*)d_in[14]; const float* be1 = (const float*)d_in[15];
    const float* g2 = (const float*)d_in[16]; const float* be2 = (const float*)d_in[17];

    char* ws = (char*)d_ws;
    u16* xb     = (u16*)(ws + 0);            // 12,582,912
    u16* WqkvT  = (u16*)(ws + 12582912);     //  3,538,944
    u16* WoT    = (u16*)(ws + 16121856);     //  1,179,648
    u16* W1T    = (u16*)(ws + 17301504);     //  3,145,728
    u16* W2T    = (u16*)(ws + 20447232);     //  3,145,728
    u16* Qb     = (u16*)(ws + 23592960);     // 12,582,912
    u16* Kb     = (u16*)(ws + 36175872);     // 12,582,912
    u16* Vtg    = (u16*)(ws + 48758784);     // 12,582,912 [B,H,Dk,S]
    u16* Ab     = (u16*)(ws + 61341696);     // 12,582,912
    u16* R1b    = (u16*)(ws + 73924608);     // 12,582,912 (resid1 = x + attnY)
    u16* X1b    = (u16*)(ws + 86507520);     // 12,582,912 (end ~99 MB)
    u16* H1b    = (u16*)(ws + 23592960);     // reuse Qb/Kb/Vtg (dead after attn)
    u16* R2b    = (u16*)(ws + 73924608);     // reuse R1b (dead after LN1)

    const dim3 blk(256);

    // 0. fused prep: x->bf16 + all 6 weight transposes
    prep_k<<<dim3(11520), blk, 0, stream>>>(x, Wq, Wk, Wv, Wo, W1, W2,
                                            xb, WqkvT, WoT, W1T, W2T);

    // 1. fused QKV projection (V pre-transposed), BK=64 global_load_lds
    qkv_gemm_k<<<dim3(64, 18), blk, 0, stream>>>(xb, WqkvT, bq, bk, bv, Qb, Kb, Vtg);

    // 2. flash attention v6 (XCD-swizzled 1-D grid)
    attn_k<<<dim3(768), blk, 0, stream>>>(Qb, Kb, Vtg, mask, Ab);

    // 3. output projection + residual: R1 = attn@Wo + bo + x
    gemm_bt64_k<<<dim3(128, 6), blk, 0, stream>>>(Ab, WoT, bo, xb, R1b,
                                                  M_TOK, D_MODEL, D_MODEL, 3);

    // 4. LN1: x1 = LN(R1) -> bf16
    ln_k<<<dim3(M_TOK), blk, 0, stream>>>(R1b, g1, be1, X1b, nullptr);

    // 5. FF1: H1 = relu(x1@W1 + b1) bf16
    gemm_bt_k<<<dim3(64, 16), blk, 0, stream>>>(X1b, W1T, b1, H1b, M_TOK, D_FF, D_MODEL, 2);

    // 6. FF2 + residual: R2 = H1@W2 + b2 + x1
    gemm_bt64_k<<<dim3(128, 6), blk, 0, stream>>>(H1b, W2T, b2, X1b, R2b,
                                                  M_TOK, D_MODEL, D_FF, 3);

    // 7. LN2: out = LN(R2) fp32 -> d_out
    ln_k<<<dim3(M_TOK), blk, 0, stream>>>(R2b, g2, be2, nullptr, (float*)d_out);
}